// Round 15
// baseline (244.284 us; speedup 1.0000x reference)
//
#include <hip/hip_runtime.h>

constexpr int B = 64, N = 1500, NT = B * N;
constexpr int E_PER = 24000, E_TOT = B * E_PER;
constexpr int E_PAD = 28512; // per-graph CSR slice, rows padded to 4
constexpr int F_INN = 128, K = 30, TOT = 97;
constexpr int LROW = 18;     // LDS row stride (16 used + 2 pad) for bank spread

// ------- CSR build: one block per graph, LOCAL node indices, pad sentinel = N ----
__global__ __launch_bounds__(1024) void build_csr(const int* __restrict__ src, const int* __restrict__ dst,
                                                  int* __restrict__ csr, int* __restrict__ rowst,
                                                  int* __restrict__ degi, float* __restrict__ degf) {
    __shared__ int hist[N];       // counts -> cursors
    __shared__ int csr_l[E_PAD];  // ~114 KB padded CSR slice
    __shared__ int wsum[4];
    int g = blockIdx.x, t = threadIdx.x;
    int gbase = g * N;
    const int* dstg = dst + (size_t)g * E_PER;
    const int* srcg = src + (size_t)g * E_PER;

    for (int i = t; i < N; i += 1024) hist[i] = 0;
    for (int i = t; i < E_PAD; i += 1024) csr_l[i] = N; // local sentinel -> zero LDS row
    __syncthreads();
    for (int e = t; e < E_PER; e += 1024)
        atomicAdd(&hist[dstg[e] - gbase], 1);
    __syncthreads();

    int local[6];
    int sum = 0, x = 0;
    if (t < 256) {
#pragma unroll
        for (int i = 0; i < 6; ++i) {
            int v = t * 6 + i;
            int d = (v < N) ? hist[v] : 0;
            local[i] = d;
            sum += (d + 3) & ~3;
        }
        x = sum;
        int lane = t & 63;
#pragma unroll
        for (int m = 1; m < 64; m <<= 1) {
            int y = __shfl_up(x, m, 64);
            if (lane >= m) x += y;
        }
        if (lane == 63) wsum[t >> 6] = x;
    }
    __syncthreads();
    if (t < 256) {
        int woff = 0;
        int wv = t >> 6;
        for (int w = 0; w < wv; ++w) woff += wsum[w];
        int run = x - sum + woff;
#pragma unroll
        for (int i = 0; i < 6; ++i) {
            int v = t * 6 + i;
            if (v < N) {
                rowst[gbase + v] = g * E_PAD + run;
                degi[gbase + v] = local[i];
                degf[gbase + v] = (float)(local[i] + 1);
                hist[v] = run;
                run += (local[i] + 3) & ~3;
            }
        }
    }
    __syncthreads();
    for (int e = t; e < E_PER; e += 1024) {
        int d = dstg[e] - gbase;
        int pos = atomicAdd(&hist[d], 1);
        csr_l[pos] = srcg[e] - gbase; // LOCAL index
    }
    __syncthreads();
    for (int i = t; i < E_PAD; i += 1024)
        csr[(size_t)g * E_PAD + i] = csr_l[i];
}

// ---------------- Tiled GEMM: t[NT,32] = h[NT,KDIM] @ W[KDIM,32] ----------------
template <int KDIM>
__global__ __launch_bounds__(256) void gemm_t(const float* __restrict__ h,
                                              const float* __restrict__ W,
                                              float* __restrict__ t) {
    __shared__ float hs[32][128];
    __shared__ float Ws[32][32];
    int tid = threadIdx.x;
    int wv = tid >> 6, lane = tid & 63;
    int v0 = blockIdx.x * 128;
    int og = wv * 8;
    float acc[2][8];
#pragma unroll
    for (int i = 0; i < 2; ++i)
#pragma unroll
        for (int j = 0; j < 8; ++j) acc[i][j] = 0.f;

    for (int kc = 0; kc < KDIM; kc += 32) {
        __syncthreads();
        {
            int n = tid >> 1, kh = (tid & 1) * 16;
            const float* hp = h + (size_t)(v0 + n) * KDIM + kc + kh;
            const float4* hp4 = reinterpret_cast<const float4*>(hp);
            float4 a = hp4[0], b = hp4[1], c = hp4[2], d = hp4[3];
            hs[kh + 0][n] = a.x;  hs[kh + 1][n] = a.y;  hs[kh + 2][n] = a.z;  hs[kh + 3][n] = a.w;
            hs[kh + 4][n] = b.x;  hs[kh + 5][n] = b.y;  hs[kh + 6][n] = b.z;  hs[kh + 7][n] = b.w;
            hs[kh + 8][n] = c.x;  hs[kh + 9][n] = c.y;  hs[kh + 10][n] = c.z; hs[kh + 11][n] = c.w;
            hs[kh + 12][n] = d.x; hs[kh + 13][n] = d.y; hs[kh + 14][n] = d.z; hs[kh + 15][n] = d.w;
        }
        {
            int r = tid >> 3, c4 = (tid & 7) * 4;
            float4 w = *reinterpret_cast<const float4*>(W + (size_t)(kc + r) * 32 + c4);
            *reinterpret_cast<float4*>(&Ws[r][c4]) = w;
        }
        __syncthreads();
#pragma unroll
        for (int k = 0; k < 32; ++k) {
            float2 hv = *reinterpret_cast<const float2*>(&hs[k][2 * lane]);
            float4 w0 = *reinterpret_cast<const float4*>(&Ws[k][og]);
            float4 w1 = *reinterpret_cast<const float4*>(&Ws[k][og + 4]);
            acc[0][0] += hv.x * w0.x; acc[0][1] += hv.x * w0.y; acc[0][2] += hv.x * w0.z; acc[0][3] += hv.x * w0.w;
            acc[0][4] += hv.x * w1.x; acc[0][5] += hv.x * w1.y; acc[0][6] += hv.x * w1.z; acc[0][7] += hv.x * w1.w;
            acc[1][0] += hv.y * w0.x; acc[1][1] += hv.y * w0.y; acc[1][2] += hv.y * w0.z; acc[1][3] += hv.y * w0.w;
            acc[1][4] += hv.y * w1.x; acc[1][5] += hv.y * w1.y; acc[1][6] += hv.y * w1.z; acc[1][7] += hv.y * w1.w;
        }
    }
#pragma unroll
    for (int i = 0; i < 2; ++i) {
        float* op = t + (size_t)(v0 + 2 * lane + i) * 32 + og;
        float4 r0 = {acc[i][0], acc[i][1], acc[i][2], acc[i][3]};
        float4 r1 = {acc[i][4], acc[i][5], acc[i][6], acc[i][7]};
        reinterpret_cast<float4*>(op)[0] = r0;
        reinterpret_cast<float4*>(op)[1] = r1;
    }
}

// ---- Aggregate from LDS: block = (graph, feature-half). 512 thr, 8 lanes/node ----
// Stages t[g][:, h*16:(h+1)*16] (1500x16 + zero sentinel row) into LDS, then
// gathers float2/lane from LDS. csr holds LOCAL indices, pad sentinel = N.
template <bool DO_W4>
__global__ __launch_bounds__(512) void agg_l(const float* __restrict__ t,
                                             const int* __restrict__ csr, const int* __restrict__ rowst,
                                             const int* __restrict__ degi, const float* __restrict__ degf,
                                             const float* __restrict__ bias, const float* __restrict__ W4,
                                             float* __restrict__ hout, float* __restrict__ t4p) {
    __shared__ float tl[(N + 1) * LROW]; // ~105.6 KB
    int bid = blockIdx.x;
    int xcd = bid & 7, j = bid >> 3;
    int g = xcd + 8 * (j >> 1); // both halves of a graph on the same XCD
    int h = j & 1;
    int gbase = g * N;
    int tid = threadIdx.x;

    // stage the half (coalesced float4), rows padded to LROW for bank spread
    const float* tg = t + (size_t)gbase * 32 + h * 16;
    for (int i = tid; i < N * 4; i += 512) {
        int v = i >> 2, j4 = (i & 3) * 4;
        float4 x = *reinterpret_cast<const float4*>(tg + (size_t)v * 32 + j4);
        *reinterpret_cast<float4*>(&tl[v * LROW + j4]) = x;
    }
    if (tid < LROW) tl[N * LROW + tid] = 0.f; // sentinel row
    __syncthreads();

    int gid = tid >> 3, f2 = tid & 7; // 64 groups of 8 lanes; lane owns 2 floats
    int fo = f2 * 2;
    float bv0 = bias[h * 16 + fo], bv1 = bias[h * 16 + fo + 1];
    float w40 = 0.f, w41 = 0.f;
    if (DO_W4) { w40 = W4[h * 16 + fo]; w41 = W4[h * 16 + fo + 1]; }

    for (int vl = gid; vl < N; vl += 64) {
        int gv = gbase + vl;
        int e0 = rowst[gv], dc = degi[gv];
        int pc = (dc + 3) & ~3;
        float2 acc = *reinterpret_cast<const float2*>(&tl[vl * LROW + fo]);
        float s0x = 0.f, s0y = 0.f, s1x = 0.f, s1y = 0.f;
        for (int e = 0; e < pc; e += 4) {
            int4 s4 = *reinterpret_cast<const int4*>(csr + e0 + e); // broadcast in group
            float2 x0 = *reinterpret_cast<const float2*>(&tl[s4.x * LROW + fo]);
            float2 x1 = *reinterpret_cast<const float2*>(&tl[s4.y * LROW + fo]);
            float2 x2 = *reinterpret_cast<const float2*>(&tl[s4.z * LROW + fo]);
            float2 x3 = *reinterpret_cast<const float2*>(&tl[s4.w * LROW + fo]);
            s0x += x0.x + x1.x; s0y += x0.y + x1.y;
            s1x += x2.x + x3.x; s1y += x2.y + x3.y;
        }
        acc.x += s0x + s1x;
        acc.y += s0y + s1y;
        float inv = 1.0f / degf[gv];
        float ox = tanhf((acc.x + bv0) * inv);
        float oy = tanhf((acc.y + bv1) * inv);
        float2 o2 = {ox, oy};
        *reinterpret_cast<float2*>(&hout[(size_t)gv * 32 + h * 16 + fo]) = o2;
        if (DO_W4) {
            float p = ox * w40 + oy * w41;
            p += __shfl_xor(p, 4, 64);
            p += __shfl_xor(p, 2, 64);
            p += __shfl_xor(p, 1, 64);
            if (f2 == 0) t4p[(size_t)h * NT + gv] = p;
        }
    }
}

// ------ Layer-4 aggregate from LDS: one block per graph, combines t4 partials ----
__global__ __launch_bounds__(512) void agg1f_l(const float* __restrict__ t4p,
                                               const int* __restrict__ csr, const int* __restrict__ rowst,
                                               const int* __restrict__ degi, const float* __restrict__ degf,
                                               const float* __restrict__ b4, float* __restrict__ h4) {
    __shared__ float ts[N + 1];
    int g = blockIdx.x, gbase = g * N, tid = threadIdx.x;
    for (int v = tid; v < N; v += 512)
        ts[v] = t4p[gbase + v] + t4p[(size_t)NT + gbase + v];
    if (tid == 0) ts[N] = 0.f;
    __syncthreads();
    float b4v = b4[0];
    for (int v = tid; v < N; v += 512) {
        int gv = gbase + v;
        int e0 = rowst[gv], dc = degi[gv];
        int pc = (dc + 3) & ~3;
        float a0 = 0.f, a1 = 0.f, a2 = 0.f, a3 = 0.f;
        for (int e = 0; e < pc; e += 4) {
            int4 s4 = *reinterpret_cast<const int4*>(csr + e0 + e);
            a0 += ts[s4.x];
            a1 += ts[s4.y];
            a2 += ts[s4.z];
            a3 += ts[s4.w];
        }
        h4[gv] = tanhf((ts[v] + (a0 + a1) + (a2 + a3) + b4v) / degf[gv]);
    }
}

// -------- Fused sortpool (radix top-K) + head: one 512-thread block/graph -----
__global__ __launch_bounds__(512) void sort_head(const float* __restrict__ hc1, const float* __restrict__ hc2,
                                                 const float* __restrict__ hc3, const float* __restrict__ h4,
                                                 const float* __restrict__ c1w, const float* __restrict__ c1b,
                                                 const float* __restrict__ c2w, const float* __restrict__ c2b,
                                                 const float* __restrict__ ow, const float* __restrict__ ob,
                                                 float* __restrict__ out) {
    __shared__ unsigned int svals[N];  // sortable key-high
    __shared__ float fvals[N];         // original h4
    __shared__ int hist[2048];
    __shared__ int canA[N], canB[N];
    __shared__ int winners[32];
    __shared__ int wsum[8];
    __shared__ int st_need, st_ncand, st_tb, st_cab, st_nwin;
    __shared__ int topk_s[K];
    __shared__ float pooled[K][TOT];
    __shared__ float c1[16][K];
    __shared__ float mp[16][16];
    __shared__ float dense[352];
    __shared__ float part[4][128];

    int g = blockIdx.x, t = threadIdx.x;
    int gbase = g * N;
    int lane = t & 63, w = t >> 6;

    for (int v = t; v < N; v += 512) {
        float f = h4[gbase + v];
        fvals[v] = f;
        unsigned int b = __float_as_uint(f);
        svals[v] = (b & 0x80000000u) ? ~b : (b | 0x80000000u);
    }
    if (t == 0) { st_need = K; st_nwin = 0; }

    auto mkkey = [&](int idx) {
        return ((unsigned long long)svals[idx] << 31) | (unsigned int)(0x7FFFFFFF - idx);
    };

    const int SHIFTS[6] = {52, 41, 30, 19, 8, 0};
    int curN = N;
    int src = 0; // 0: implicit [0,N), 1: canA, 2: canB
    for (int pass = 0; pass < 6; ++pass) {
        int shift = SHIFTS[pass];
        int mask = (pass == 5) ? 0xFF : 0x7FF;
        for (int i = t; i < 2048; i += 512) hist[i] = 0;
        if (t == 0) st_ncand = 0;
        __syncthreads();
        for (int i = t; i < curN; i += 512) {
            int idx = (src == 0) ? i : (src == 1 ? canA[i] : canB[i]);
            int d = (int)((mkkey(idx) >> shift) & mask);
            atomicAdd(&hist[d], 1);
        }
        __syncthreads();
        int need = st_need;
        int c[4];
        int s = 0;
#pragma unroll
        for (int u = 0; u < 4; ++u) { c[u] = hist[2047 - (4 * t + u)]; s += c[u]; }
        int x = s;
#pragma unroll
        for (int m = 1; m < 64; m <<= 1) {
            int y = __shfl_up(x, m, 64);
            if (lane >= m) x += y;
        }
        if (lane == 63) wsum[w] = x;
        __syncthreads();
        int woff = 0;
        for (int ww = 0; ww < w; ++ww) woff += wsum[ww];
        int A = woff + x - s;
#pragma unroll
        for (int u = 0; u < 4; ++u) {
            if (A < need && need <= A + c[u]) { st_tb = 2047 - (4 * t + u); st_cab = A; }
            A += c[u];
        }
        __syncthreads();
        int tb = st_tb, cab = st_cab;
        int* dst = (src == 1) ? canB : canA;
        for (int i = t; i < curN; i += 512) {
            int idx = (src == 0) ? i : (src == 1 ? canA[i] : canB[i]);
            int d = (int)((mkkey(idx) >> shift) & mask);
            if (d > tb) {
                int p = atomicAdd(&st_nwin, 1);
                winners[p] = idx;
            } else if (d == tb) {
                int p = atomicAdd(&st_ncand, 1);
                dst[p] = idx;
            }
        }
        __syncthreads();
        int ncand = st_ncand;
        need -= cab;
        if (t == 0) st_need = need;
        if (ncand == need) {
            int base = st_nwin;
            for (int i = t; i < ncand; i += 512) winners[base + i] = dst[i];
            __syncthreads();
            break;
        }
        curN = ncand;
        src = (src == 1) ? 2 : 1;
        __syncthreads();
    }

    // exact ordering: bitonic sort of the 30 winner keys on wave 0
    if (t < 64) {
        unsigned long long key = (t < K) ? mkkey(winners[t]) : 0ull;
        unsigned long long kk = ~key;
#pragma unroll
        for (int k = 2; k <= 64; k <<= 1) {
#pragma unroll
            for (int j = k >> 1; j > 0; j >>= 1) {
                unsigned long long o = __shfl_xor(kk, j, 64);
                bool keepMin = ((t & j) == 0) == ((t & k) == 0);
                kk = keepMin ? (kk < o ? kk : o) : (kk > o ? kk : o);
            }
        }
        key = ~kk;
        if (t < K) topk_s[t] = 0x7FFFFFFF - (int)(unsigned int)(key & 0x7FFFFFFFu);
    }
    __syncthreads();

    for (int i = t; i < K * TOT; i += 512) {
        int k = i / TOT, d = i % TOT;
        int vloc = topk_s[k];
        int gi = gbase + vloc;
        float val = (d < 32) ? hc1[(size_t)gi * 32 + d]
                  : (d < 64) ? hc2[(size_t)gi * 32 + d - 32]
                  : (d < 96) ? hc3[(size_t)gi * 32 + d - 64]
                             : fvals[vloc];
        pooled[k][d] = val;
    }
    __syncthreads();
    for (int i = t; i < 16 * K; i += 512) {
        int o = i / K, k = i % K;
        float s = c1b[o];
        for (int d = 0; d < TOT; ++d) s += pooled[k][d] * c1w[o * TOT + d];
        c1[o][k] = fmaxf(s, 0.f);
    }
    __syncthreads();
    for (int i = t; i < 16 * 15; i += 512) {
        int o = i / 15, p = i % 15;
        mp[o][p] = fmaxf(c1[o][2 * p], c1[o][2 * p + 1]);
    }
    __syncthreads();
    for (int i = t; i < 352; i += 512) {
        int o = i / 11, p = i % 11;
        float s = c2b[o];
#pragma unroll
        for (int ci = 0; ci < 16; ++ci)
#pragma unroll
            for (int tt = 0; tt < 5; ++tt)
                s += mp[ci][p + tt] * c2w[(o * 16 + ci) * 5 + tt];
        dense[i] = fmaxf(s, 0.f);
    }
    __syncthreads();
    {
        int o = t & 127, q = t >> 7;
        float s = 0.f;
        for (int m = q * 88; m < (q + 1) * 88; ++m) s += dense[m] * ow[m * 128 + o];
        part[q][o] = s;
    }
    __syncthreads();
    if (t < 128) {
        float s = (part[0][t] + part[1][t]) + (part[2][t] + part[3][t]) + ob[t];
        out[g * 128 + t] = fmaxf(s, 0.f);
    }
}

extern "C" void kernel_launch(void* const* d_in, const int* in_sizes, int n_in,
                              void* d_out, int out_size, void* d_ws, size_t ws_size,
                              hipStream_t stream) {
    const float* node_feat = (const float*)d_in[0];
    const int* esrc = (const int*)d_in[1];
    const int* edst = (const int*)d_in[2];
    const float* W1 = (const float*)d_in[3];
    const float* b1 = (const float*)d_in[4];
    const float* W2 = (const float*)d_in[5];
    const float* b2 = (const float*)d_in[6];
    const float* W3 = (const float*)d_in[7];
    const float* b3 = (const float*)d_in[8];
    const float* W4 = (const float*)d_in[9];
    const float* b4 = (const float*)d_in[10];
    const float* c1w = (const float*)d_in[11];
    const float* c1b = (const float*)d_in[12];
    const float* c2w = (const float*)d_in[13];
    const float* c2b = (const float*)d_in[14];
    const float* ow = (const float*)d_in[15];
    const float* ob = (const float*)d_in[16];

    char* ws = (char*)d_ws;
    size_t off = 0;
    auto alloc = [&](size_t bytes) {
        size_t r = off;
        off += (bytes + 255) & ~(size_t)255;
        return r;
    };
    int* deg_i = (int*)(ws + alloc((size_t)NT * 4));
    int* rowst = (int*)(ws + alloc((size_t)NT * 4));
    float* degf = (float*)(ws + alloc((size_t)NT * 4));
    int* csr = (int*)(ws + alloc((size_t)B * E_PAD * 4));
    float* tA = (float*)(ws + alloc((size_t)NT * 32 * 4));
    float* tB = (float*)(ws + alloc((size_t)NT * 32 * 4));
    float* hc1 = (float*)(ws + alloc((size_t)NT * 32 * 4));
    float* hc2 = (float*)(ws + alloc((size_t)NT * 32 * 4));
    float* hc3 = (float*)(ws + alloc((size_t)NT * 32 * 4));
    float* t4p = (float*)(ws + alloc((size_t)2 * NT * 4));
    float* h4 = (float*)(ws + alloc((size_t)NT * 4));

    build_csr<<<B, 1024, 0, stream>>>(esrc, edst, csr, rowst, deg_i, degf);

    gemm_t<F_INN><<<NT / 128, 256, 0, stream>>>(node_feat, W1, tA);
    agg_l<false><<<B * 2, 512, 0, stream>>>(tA, csr, rowst, deg_i, degf, b1, nullptr, hc1, nullptr);
    gemm_t<32><<<NT / 128, 256, 0, stream>>>(hc1, W2, tB);
    agg_l<false><<<B * 2, 512, 0, stream>>>(tB, csr, rowst, deg_i, degf, b2, nullptr, hc2, nullptr);
    gemm_t<32><<<NT / 128, 256, 0, stream>>>(hc2, W3, tA);
    agg_l<true><<<B * 2, 512, 0, stream>>>(tA, csr, rowst, deg_i, degf, b3, W4, hc3, t4p);
    agg1f_l<<<B, 512, 0, stream>>>(t4p, csr, rowst, deg_i, degf, b4, h4);

    sort_head<<<B, 512, 0, stream>>>(hc1, hc2, hc3, h4, c1w, c1b, c2w, c2b, ow, ob, (float*)d_out);
}

// Round 16
// 120.175 us; speedup vs baseline: 2.0327x; 2.0327x over previous
//
#include <hip/hip_runtime.h>

constexpr int B = 64, N = 1500, NT = B * N;
constexpr int E_PER = 24000, E_TOT = B * E_PER;
constexpr int E_PAD = 28512; // per-graph CSR slice, rows padded to 4
constexpr int F_INN = 128, K = 30, TOT = 97;
constexpr int NB_G = 47;     // blocks per graph in agg_f (47*32 >= 1500)
constexpr int GEMM_TILES = NT / 128;            // 750
constexpr int GEMM_BLKS = (GEMM_TILES + 3) / 4; // 188

// ------ prep: heterogeneous kernel. Blocks [0,B): CSR build (one graph each,
// global indices, pad sentinel NT, zeroes sentinel rows). Blocks [B, B+188):
// t[NT,32] = node_feat @ W1 as 4 x 256-thread sub-blocks per block.
__global__ __launch_bounds__(1024) void prep(const int* __restrict__ src, const int* __restrict__ dst,
                                             int* __restrict__ csr, int* __restrict__ rowst,
                                             int* __restrict__ degi, float* __restrict__ degf,
                                             float* __restrict__ tA, float* __restrict__ tB,
                                             float* __restrict__ t4,
                                             const float* __restrict__ nf, const float* __restrict__ W1) {
    __shared__ union {
        struct { int hist[N]; int csr_l[E_PAD]; int wsum[4]; } c; // ~120 KB
        struct { float hs[4][32][128]; float Ws[4][32][32]; } g;  // 80 KB
    } u;
    int bid = blockIdx.x, t = threadIdx.x;

    if (bid < B) { // ---------------- CSR build path ----------------
        int g = bid;
        int gbase = g * N;
        const int* dstg = dst + (size_t)g * E_PER;
        const int* srcg = src + (size_t)g * E_PER;

        if (g == 0) { // zero sentinel rows (row NT)
            if (t < 32) tA[(size_t)NT * 32 + t] = 0.f;
            else if (t < 64) tB[(size_t)NT * 32 + (t - 32)] = 0.f;
            else if (t == 64) t4[NT] = 0.f;
        }

        for (int i = t; i < N; i += 1024) u.c.hist[i] = 0;
        for (int i = t; i < E_PAD; i += 1024) u.c.csr_l[i] = NT; // sentinel -> zero row
        __syncthreads();
        for (int e = t; e < E_PER; e += 1024)
            atomicAdd(&u.c.hist[dstg[e] - gbase], 1);
        __syncthreads();

        int local[6];
        int sum = 0, x = 0;
        if (t < 256) {
#pragma unroll
            for (int i = 0; i < 6; ++i) {
                int v = t * 6 + i;
                int d = (v < N) ? u.c.hist[v] : 0;
                local[i] = d;
                sum += (d + 3) & ~3;
            }
            x = sum;
            int lane = t & 63;
#pragma unroll
            for (int m = 1; m < 64; m <<= 1) {
                int y = __shfl_up(x, m, 64);
                if (lane >= m) x += y;
            }
            if (lane == 63) u.c.wsum[t >> 6] = x;
        }
        __syncthreads();
        if (t < 256) {
            int woff = 0;
            int wv = t >> 6;
            for (int w = 0; w < wv; ++w) woff += u.c.wsum[w];
            int run = x - sum + woff;
#pragma unroll
            for (int i = 0; i < 6; ++i) {
                int v = t * 6 + i;
                if (v < N) {
                    rowst[gbase + v] = g * E_PAD + run;
                    degi[gbase + v] = local[i];
                    degf[gbase + v] = (float)(local[i] + 1);
                    u.c.hist[v] = run;
                    run += (local[i] + 3) & ~3;
                }
            }
        }
        __syncthreads();
        for (int e = t; e < E_PER; e += 1024) {
            int d = dstg[e] - gbase;
            int pos = atomicAdd(&u.c.hist[d], 1);
            u.c.csr_l[pos] = srcg[e]; // GLOBAL index
        }
        __syncthreads();
        for (int i = t; i < E_PAD; i += 1024)
            csr[(size_t)g * E_PAD + i] = u.c.csr_l[i];
    } else { // ---------------- GEMM path: 4 sub-blocks of 256 ----------------
        int sub = t >> 8, tid = t & 255;
        int tile = (bid - B) * 4 + sub;
        bool valid = tile < GEMM_TILES;
        int wv = tid >> 6, lane = tid & 63;
        int v0 = tile * 128;
        int og = wv * 8;
        float acc[2][8];
#pragma unroll
        for (int i = 0; i < 2; ++i)
#pragma unroll
            for (int j = 0; j < 8; ++j) acc[i][j] = 0.f;

        for (int kc = 0; kc < F_INN; kc += 32) {
            __syncthreads();
            if (valid) {
                int n = tid >> 1, kh = (tid & 1) * 16;
                const float* hp = nf + (size_t)(v0 + n) * F_INN + kc + kh;
                const float4* hp4 = reinterpret_cast<const float4*>(hp);
                float4 a = hp4[0], b = hp4[1], c = hp4[2], d = hp4[3];
                float (*hs)[128] = u.g.hs[sub];
                hs[kh + 0][n] = a.x;  hs[kh + 1][n] = a.y;  hs[kh + 2][n] = a.z;  hs[kh + 3][n] = a.w;
                hs[kh + 4][n] = b.x;  hs[kh + 5][n] = b.y;  hs[kh + 6][n] = b.z;  hs[kh + 7][n] = b.w;
                hs[kh + 8][n] = c.x;  hs[kh + 9][n] = c.y;  hs[kh + 10][n] = c.z; hs[kh + 11][n] = c.w;
                hs[kh + 12][n] = d.x; hs[kh + 13][n] = d.y; hs[kh + 14][n] = d.z; hs[kh + 15][n] = d.w;
                int r = tid >> 3, c4 = (tid & 7) * 4;
                float4 w = *reinterpret_cast<const float4*>(W1 + (size_t)(kc + r) * 32 + c4);
                *reinterpret_cast<float4*>(&u.g.Ws[sub][r][c4]) = w;
            }
            __syncthreads();
            if (valid) {
#pragma unroll
                for (int k = 0; k < 32; ++k) {
                    float2 hv = *reinterpret_cast<const float2*>(&u.g.hs[sub][k][2 * lane]);
                    float4 w0 = *reinterpret_cast<const float4*>(&u.g.Ws[sub][k][og]);
                    float4 w1 = *reinterpret_cast<const float4*>(&u.g.Ws[sub][k][og + 4]);
                    acc[0][0] += hv.x * w0.x; acc[0][1] += hv.x * w0.y; acc[0][2] += hv.x * w0.z; acc[0][3] += hv.x * w0.w;
                    acc[0][4] += hv.x * w1.x; acc[0][5] += hv.x * w1.y; acc[0][6] += hv.x * w1.z; acc[0][7] += hv.x * w1.w;
                    acc[1][0] += hv.y * w0.x; acc[1][1] += hv.y * w0.y; acc[1][2] += hv.y * w0.z; acc[1][3] += hv.y * w0.w;
                    acc[1][4] += hv.y * w1.x; acc[1][5] += hv.y * w1.y; acc[1][6] += hv.y * w1.z; acc[1][7] += hv.y * w1.w;
                }
            }
        }
        if (valid) {
#pragma unroll
            for (int i = 0; i < 2; ++i) {
                float* op = tA + (size_t)(v0 + 2 * lane + i) * 32 + og;
                float4 r0 = {acc[i][0], acc[i][1], acc[i][2], acc[i][3]};
                float4 r1 = {acc[i][4], acc[i][5], acc[i][6], acc[i][7]};
                reinterpret_cast<float4*>(op)[0] = r0;
                reinterpret_cast<float4*>(op)[1] = r1;
            }
        }
    }
}

// ---- Aggregate (float4 lanes, 8 lanes/node) + fused transform; XCD swizzle ----
// t has NT+1 rows; row NT is zero (sentinel for CSR padding).
template <int FUSE>
__global__ __launch_bounds__(256) void agg_f(const float* __restrict__ t,
                                             const int* __restrict__ csr, const int* __restrict__ rowst,
                                             const int* __restrict__ degi, const float* __restrict__ degf,
                                             const float* __restrict__ bias, const float* __restrict__ Wn,
                                             float* __restrict__ hout, float* __restrict__ tn) {
    __shared__ float Ws[1024];
    __shared__ float outs[32][32];
    if (FUSE == 32) {
        for (int i = threadIdx.x; i < 1024; i += 256) Ws[i] = Wn[i];
    }
    int bid = blockIdx.x;
    int xcd = bid & 7, j = bid >> 3;
    int g = xcd + 8 * (j / NB_G);
    int nb = j % NB_G;
    int nl = threadIdx.x >> 3; // node within block [0,32)
    int f4 = threadIdx.x & 7;  // float4 slot [0,8)
    int vl = nb * 32 + nl;
    bool valid = vl < N;
    int v = g * N + vl;
    const float4* t4v = reinterpret_cast<const float4*>(t);
    float4 out = {0.f, 0.f, 0.f, 0.f};
    if (valid) {
        float4 acc = t4v[(unsigned)(v * 8 + f4)];
        int e0 = rowst[v];
        int dc = degi[v];
        int pc = (dc + 3) & ~3;
        float4 s1 = {0.f, 0.f, 0.f, 0.f}, s2 = {0.f, 0.f, 0.f, 0.f};
        for (int e = 0; e < pc; e += 4) {
            int4 s4 = *reinterpret_cast<const int4*>(csr + e0 + e);
            float4 x0 = t4v[(unsigned)(s4.x * 8 + f4)];
            float4 x1 = t4v[(unsigned)(s4.y * 8 + f4)];
            float4 x2 = t4v[(unsigned)(s4.z * 8 + f4)];
            float4 x3 = t4v[(unsigned)(s4.w * 8 + f4)];
            s1.x += x0.x + x1.x; s1.y += x0.y + x1.y; s1.z += x0.z + x1.z; s1.w += x0.w + x1.w;
            s2.x += x2.x + x3.x; s2.y += x2.y + x3.y; s2.z += x2.z + x3.z; s2.w += x2.w + x3.w;
        }
        acc.x += s1.x + s2.x; acc.y += s1.y + s2.y; acc.z += s1.z + s2.z; acc.w += s1.w + s2.w;
        float4 bv = *reinterpret_cast<const float4*>(bias + f4 * 4);
        float inv = 1.0f / degf[v];
        out.x = tanhf((acc.x + bv.x) * inv);
        out.y = tanhf((acc.y + bv.y) * inv);
        out.z = tanhf((acc.z + bv.z) * inv);
        out.w = tanhf((acc.w + bv.w) * inv);
        reinterpret_cast<float4*>(hout)[(unsigned)(v * 8 + f4)] = out;
    }
    if (FUSE == 32) {
        *reinterpret_cast<float4*>(&outs[nl][f4 * 4]) = out;
        __syncthreads();
        if (valid) {
            float4 s = {0.f, 0.f, 0.f, 0.f};
#pragma unroll
            for (int ff = 0; ff < 32; ++ff) {
                float h = outs[nl][ff];
                float4 wr = *reinterpret_cast<const float4*>(&Ws[ff * 32 + f4 * 4]);
                s.x += h * wr.x; s.y += h * wr.y; s.z += h * wr.z; s.w += h * wr.w;
            }
            reinterpret_cast<float4*>(tn)[(unsigned)(v * 8 + f4)] = s;
        }
    } else if (valid) {
        float4 w4 = *reinterpret_cast<const float4*>(Wn + f4 * 4);
        float p = out.x * w4.x + out.y * w4.y + out.z * w4.z + out.w * w4.w;
        p += __shfl_xor(p, 4, 64);
        p += __shfl_xor(p, 2, 64);
        p += __shfl_xor(p, 1, 64);
        if (f4 == 0) tn[v] = p;
    }
}

// -------- Fused layer4-agg + sortpool (radix top-K) + head: 512 thr/graph -----
__global__ __launch_bounds__(512) void sort_head(const float* __restrict__ hc1, const float* __restrict__ hc2,
                                                 const float* __restrict__ hc3, const float* __restrict__ t4,
                                                 const int* __restrict__ csr, const int* __restrict__ rowst,
                                                 const int* __restrict__ degi, const float* __restrict__ degf,
                                                 const float* __restrict__ b4,
                                                 const float* __restrict__ c1w, const float* __restrict__ c1b,
                                                 const float* __restrict__ c2w, const float* __restrict__ c2b,
                                                 const float* __restrict__ ow, const float* __restrict__ ob,
                                                 float* __restrict__ out) {
    __shared__ float ts[N + 1];        // t4 slice (sentinel at N)
    __shared__ unsigned int svals[N];  // sortable key-high
    __shared__ float fvals[N];         // h4
    __shared__ int hist[2048];
    __shared__ int canA[N], canB[N];
    __shared__ int winners[32];
    __shared__ int wsum[8];
    __shared__ int st_need, st_ncand, st_tb, st_cab, st_nwin;
    __shared__ int topk_s[K];
    __shared__ float pooled[K][TOT];
    __shared__ float c1[16][K];
    __shared__ float mp[16][16];
    __shared__ float dense[352];
    __shared__ float part[4][128];

    int g = blockIdx.x, t = threadIdx.x;
    int gbase = g * N;
    int lane = t & 63, w = t >> 6;

    // ---- fused layer-4 aggregation (reads t4 slice via LDS) ----
    for (int v = t; v < N; v += 512) ts[v] = t4[gbase + v];
    if (t == 0) ts[N] = 0.f;
    if (t == 1) { st_need = K; st_nwin = 0; }
    __syncthreads();
    {
        float b4v = b4[0];
        for (int v = t; v < N; v += 512) {
            int gv = gbase + v;
            int e0 = rowst[gv], dc = degi[gv];
            int pc = (dc + 3) & ~3;
            float a0 = 0.f, a1 = 0.f, a2 = 0.f, a3 = 0.f;
            for (int e = 0; e < pc; e += 4) {
                int4 s4 = *reinterpret_cast<const int4*>(csr + e0 + e);
                unsigned l0 = min((unsigned)(s4.x - gbase), (unsigned)N);
                unsigned l1 = min((unsigned)(s4.y - gbase), (unsigned)N);
                unsigned l2 = min((unsigned)(s4.z - gbase), (unsigned)N);
                unsigned l3 = min((unsigned)(s4.w - gbase), (unsigned)N);
                a0 += ts[l0];
                a1 += ts[l1];
                a2 += ts[l2];
                a3 += ts[l3];
            }
            float h = tanhf((ts[v] + (a0 + a1) + (a2 + a3) + b4v) / degf[gv]);
            fvals[v] = h;
            unsigned int b = __float_as_uint(h);
            svals[v] = (b & 0x80000000u) ? ~b : (b | 0x80000000u);
        }
    }
    __syncthreads();

    auto mkkey = [&](int idx) {
        return ((unsigned long long)svals[idx] << 31) | (unsigned int)(0x7FFFFFFF - idx);
    };

    const int SHIFTS[6] = {52, 41, 30, 19, 8, 0};
    int curN = N;
    int src = 0; // 0: implicit [0,N), 1: canA, 2: canB
    for (int pass = 0; pass < 6; ++pass) {
        int shift = SHIFTS[pass];
        int mask = (pass == 5) ? 0xFF : 0x7FF;
        for (int i = t; i < 2048; i += 512) hist[i] = 0;
        if (t == 0) st_ncand = 0;
        __syncthreads();
        for (int i = t; i < curN; i += 512) {
            int idx = (src == 0) ? i : (src == 1 ? canA[i] : canB[i]);
            int d = (int)((mkkey(idx) >> shift) & mask);
            atomicAdd(&hist[d], 1);
        }
        __syncthreads();
        int need = st_need;
        int c[4];
        int s = 0;
#pragma unroll
        for (int u = 0; u < 4; ++u) { c[u] = hist[2047 - (4 * t + u)]; s += c[u]; }
        int x = s;
#pragma unroll
        for (int m = 1; m < 64; m <<= 1) {
            int y = __shfl_up(x, m, 64);
            if (lane >= m) x += y;
        }
        if (lane == 63) wsum[w] = x;
        __syncthreads();
        int woff = 0;
        for (int ww = 0; ww < w; ++ww) woff += wsum[ww];
        int A = woff + x - s;
#pragma unroll
        for (int u = 0; u < 4; ++u) {
            if (A < need && need <= A + c[u]) { st_tb = 2047 - (4 * t + u); st_cab = A; }
            A += c[u];
        }
        __syncthreads();
        int tb = st_tb, cab = st_cab;
        int* dst = (src == 1) ? canB : canA;
        for (int i = t; i < curN; i += 512) {
            int idx = (src == 0) ? i : (src == 1 ? canA[i] : canB[i]);
            int d = (int)((mkkey(idx) >> shift) & mask);
            if (d > tb) {
                int p = atomicAdd(&st_nwin, 1);
                winners[p] = idx;
            } else if (d == tb) {
                int p = atomicAdd(&st_ncand, 1);
                dst[p] = idx;
            }
        }
        __syncthreads();
        int ncand = st_ncand;
        need -= cab;
        if (t == 0) st_need = need;
        if (ncand == need) {
            int base = st_nwin;
            for (int i = t; i < ncand; i += 512) winners[base + i] = dst[i];
            __syncthreads();
            break;
        }
        curN = ncand;
        src = (src == 1) ? 2 : 1;
        __syncthreads();
    }

    // exact ordering: bitonic sort of the 30 winner keys on wave 0
    if (t < 64) {
        unsigned long long key = (t < K) ? mkkey(winners[t]) : 0ull;
        unsigned long long kk = ~key;
#pragma unroll
        for (int k = 2; k <= 64; k <<= 1) {
#pragma unroll
            for (int j = k >> 1; j > 0; j >>= 1) {
                unsigned long long o = __shfl_xor(kk, j, 64);
                bool keepMin = ((t & j) == 0) == ((t & k) == 0);
                kk = keepMin ? (kk < o ? kk : o) : (kk > o ? kk : o);
            }
        }
        key = ~kk;
        if (t < K) topk_s[t] = 0x7FFFFFFF - (int)(unsigned int)(key & 0x7FFFFFFFu);
    }
    __syncthreads();

    for (int i = t; i < K * TOT; i += 512) {
        int k = i / TOT, d = i % TOT;
        int vloc = topk_s[k];
        int gi = gbase + vloc;
        float val = (d < 32) ? hc1[(size_t)gi * 32 + d]
                  : (d < 64) ? hc2[(size_t)gi * 32 + d - 32]
                  : (d < 96) ? hc3[(size_t)gi * 32 + d - 64]
                             : fvals[vloc];
        pooled[k][d] = val;
    }
    __syncthreads();
    for (int i = t; i < 16 * K; i += 512) {
        int o = i / K, k = i % K;
        float s = c1b[o];
        for (int d = 0; d < TOT; ++d) s += pooled[k][d] * c1w[o * TOT + d];
        c1[o][k] = fmaxf(s, 0.f);
    }
    __syncthreads();
    for (int i = t; i < 16 * 15; i += 512) {
        int o = i / 15, p = i % 15;
        mp[o][p] = fmaxf(c1[o][2 * p], c1[o][2 * p + 1]);
    }
    __syncthreads();
    for (int i = t; i < 352; i += 512) {
        int o = i / 11, p = i % 11;
        float s = c2b[o];
#pragma unroll
        for (int ci = 0; ci < 16; ++ci)
#pragma unroll
            for (int tt = 0; tt < 5; ++tt)
                s += mp[ci][p + tt] * c2w[(o * 16 + ci) * 5 + tt];
        dense[i] = fmaxf(s, 0.f);
    }
    __syncthreads();
    {
        int o = t & 127, q = t >> 7;
        float s = 0.f;
        for (int m = q * 88; m < (q + 1) * 88; ++m) s += dense[m] * ow[m * 128 + o];
        part[q][o] = s;
    }
    __syncthreads();
    if (t < 128) {
        float s = (part[0][t] + part[1][t]) + (part[2][t] + part[3][t]) + ob[t];
        out[g * 128 + t] = fmaxf(s, 0.f);
    }
}

extern "C" void kernel_launch(void* const* d_in, const int* in_sizes, int n_in,
                              void* d_out, int out_size, void* d_ws, size_t ws_size,
                              hipStream_t stream) {
    const float* node_feat = (const float*)d_in[0];
    const int* esrc = (const int*)d_in[1];
    const int* edst = (const int*)d_in[2];
    const float* W1 = (const float*)d_in[3];
    const float* b1 = (const float*)d_in[4];
    const float* W2 = (const float*)d_in[5];
    const float* b2 = (const float*)d_in[6];
    const float* W3 = (const float*)d_in[7];
    const float* b3 = (const float*)d_in[8];
    const float* W4 = (const float*)d_in[9];
    const float* b4 = (const float*)d_in[10];
    const float* c1w = (const float*)d_in[11];
    const float* c1b = (const float*)d_in[12];
    const float* c2w = (const float*)d_in[13];
    const float* c2b = (const float*)d_in[14];
    const float* ow = (const float*)d_in[15];
    const float* ob = (const float*)d_in[16];

    char* ws = (char*)d_ws;
    size_t off = 0;
    auto alloc = [&](size_t bytes) {
        size_t r = off;
        off += (bytes + 255) & ~(size_t)255;
        return r;
    };
    int* deg_i = (int*)(ws + alloc((size_t)NT * 4));
    int* rowst = (int*)(ws + alloc((size_t)NT * 4));
    float* degf = (float*)(ws + alloc((size_t)NT * 4));
    int* csr = (int*)(ws + alloc((size_t)B * E_PAD * 4));
    float* tA = (float*)(ws + alloc((size_t)(NT + 1) * 32 * 4)); // +1 zero sentinel row
    float* tB = (float*)(ws + alloc((size_t)(NT + 1) * 32 * 4));
    float* hc1 = (float*)(ws + alloc((size_t)NT * 32 * 4));
    float* hc2 = (float*)(ws + alloc((size_t)NT * 32 * 4));
    float* hc3 = (float*)(ws + alloc((size_t)NT * 32 * 4));
    float* t4 = (float*)(ws + alloc((size_t)(NT + 1) * 4));

    prep<<<B + GEMM_BLKS, 1024, 0, stream>>>(esrc, edst, csr, rowst, deg_i, degf,
                                             tA, tB, t4, node_feat, W1);

    agg_f<32><<<8 * NB_G * 8, 256, 0, stream>>>(tA, csr, rowst, deg_i, degf, b1, W2, hc1, tB);
    agg_f<32><<<8 * NB_G * 8, 256, 0, stream>>>(tB, csr, rowst, deg_i, degf, b2, W3, hc2, tA);
    agg_f<1><<<8 * NB_G * 8, 256, 0, stream>>>(tA, csr, rowst, deg_i, degf, b3, W4, hc3, t4);

    sort_head<<<B, 512, 0, stream>>>(hc1, hc2, hc3, t4, csr, rowst, deg_i, degf, b4,
                                     c1w, c1b, c2w, c2b, ow, ob, (float*)d_out);
}